// Round 6
// baseline (318.998 us; speedup 1.0000x reference)
//
#include <hip/hip_runtime.h>
#include <math.h>

// Problem constants (fixed by setup_inputs)
#define BB   16
#define HW   65536          // 256*256
#define NPIX (BB * HW)      // 1,048,576
#define NT   256
#define PPT  4
#define NBLK (NPIX / (NT * PPT))   // 1024 blocks
#define BPI  (NBLK / BB)           // 64 blocks per image

// ws layout (bytes)
#define UARR_OFF  0ull                              // 4 MB
#define CLSL_OFF  (4ull << 20)                      // 4 MB
// 9 partial arrays of NBLK floats (plain stores):
//  0 pos  1 neg  2 s1  3 m1  4 s0  5 m0  6 wcl  7 selcnt  8 selsum
#define PART_OFF  (8ull << 20)
#define STATS_OFF ((8ull << 20) + (64ull << 10))    // 16 u32 thresholds
#define CTR_OFF   ((8ull << 20) + (128ull << 10))   // 17 u32 counters (memset 128 B)

// monotone unsigned mapping of float bits (ascending float -> ascending uint)
__device__ __forceinline__ unsigned fmap(float x) {
  unsigned b = __float_as_uint(x);
  return (b & 0x80000000u) ? ~b : (b | 0x80000000u);
}

// log(1 + e^{-|d|}) with native exp/log: arg of log is in (1,2] -> accurate
__device__ __forceinline__ float softplus_neg_abs(float d) {
  return __logf(1.f + __expf(-fabsf(d)));
}

// Crossing search for rank k in an LDS histogram (nbins multiple of 256).
// Exactly one thread writes *sh_bin/*sh_rank; trailing __syncthreads.
__device__ __forceinline__ void histSelect(unsigned* lhist, int nbins, unsigned k,
                                           unsigned* wt, unsigned* sh_bin,
                                           unsigned* sh_rank) {
  int lane = threadIdx.x & 63, wave = threadIdx.x >> 6;
  int per = nbins >> 8;
  unsigned s = 0;
  for (int j = 0; j < per; j++) s += lhist[threadIdx.x * per + j];
  unsigned x = s;
  for (int o = 1; o < 64; o <<= 1) { unsigned v = __shfl_up(x, o, 64); if (lane >= o) x += v; }
  if (lane == 63) wt[wave] = x;
  __syncthreads();
  unsigned woff = 0;
  for (int w = 0; w < wave; w++) woff += wt[w];
  unsigned incl = x + woff, excl = incl - s;
  if (excl < k && k <= incl) {
    unsigned cum = excl;
    for (int j = 0; j < per; j++) {
      unsigned c = lhist[threadIdx.x * per + j];
      if (k <= cum + c) { *sh_bin = (unsigned)(threadIdx.x * per + j); *sh_rank = k - cum; break; }
      cum += c;
    }
  }
  __syncthreads();
}

// kMain: per-pixel compute + stores; per-image LAST BLOCK (device-scope
// atomic arrival) computes the exact OHEM threshold in-LDS.
__global__ void kMain(const float* __restrict__ target, const float* __restrict__ logits,
                      unsigned* __restrict__ uarr, float* __restrict__ clsl,
                      float* __restrict__ part, unsigned* __restrict__ stats,
                      unsigned* __restrict__ ctr) {
  __shared__ float red[7][4];
  __shared__ unsigned lhist[4096];
  __shared__ unsigned wt[4];
  __shared__ unsigned sh_t, sh_np, sh_nn, shb, shr;

  const int blk = blockIdx.x;
  const int tid = blk * NT + threadIdx.x;
  const int p0 = tid * PPT;          // 4 consecutive pixels, same image
  const int b = p0 >> 16;
  const int hw = p0 & 65535;
  const int lane = threadIdx.x & 63, wave = threadIdx.x >> 6;

  // ---- per-pixel compute (round-4 structure, global hist atomics removed)
  const float4* t4 = (const float4*)(target + (size_t)p0 * 10);
  const float* lg = logits + (size_t)b * 10 * HW + hw;
  float4 T[10], L[10];
#pragma unroll
  for (int j = 0; j < 10; j++) T[j] = t4[j];
#pragma unroll
  for (int c = 0; c < 10; c++) L[c] = *(const float4*)(lg + (size_t)c * HW);

  float tf[40], lf[40];
#pragma unroll
  for (int j = 0; j < 10; j++) {
    tf[4 * j] = T[j].x; tf[4 * j + 1] = T[j].y; tf[4 * j + 2] = T[j].z; tf[4 * j + 3] = T[j].w;
    lf[4 * j] = L[j].x; lf[4 * j + 1] = L[j].y; lf[4 * j + 2] = L[j].z; lf[4 * j + 3] = L[j].w;
  }

  float cpos = 0.f, cneg = 0.f, s1 = 0.f, m1 = 0.f, s0 = 0.f, m0 = 0.f, wcl = 0.f;
  float cl4[4];
  unsigned uu[4];
#pragma unroll
  for (int q = 0; q < 4; q++) {
    float label = tf[10 * q];
    float wgt   = tf[10 * q + 1];
    bool pos = label > 0.f;
    bool neg = label == 0.f;
    float l0 = lf[0 * 4 + q], l1 = lf[1 * 4 + q];
    float d = l0 - l1;
    float cl = fmaxf(l0, l1) + softplus_neg_abs(d) - (pos ? l1 : l0);
    cl4[q] = cl;
    wcl += cl * wgt;
    cpos += pos ? 1.f : 0.f;
    cneg += neg ? 1.f : 0.f;
    unsigned u = fmap(d);            // score = sigmoid(d) monotone in d
    uu[q] = neg ? u : 0xFFFFFFFFu;   // finite d never maps to 0xFFFFFFFF
#pragma unroll
    for (int n = 0; n < 4; n++) {
      float a = lf[(2 + n) * 4 + q]; // class-0 logit
      float c = lf[(6 + n) * 4 + q]; // class-1 logit
      float ce0 = fmaxf(a, c) + softplus_neg_abs(a - c);
      int lab = (int)tf[10 * q + 2 + n];
      float ce = ce0 - (lab ? c : a);
      float w = tf[10 * q + 6 + n];
      if (lab) { m1 += w; s1 += w * ce; }
      else     { m0 += w; s0 += w * ce; }
    }
  }
  *(float4*)(clsl + p0) = make_float4(cl4[0], cl4[1], cl4[2], cl4[3]);
  *(uint4*)(uarr + p0)  = make_uint4(uu[0], uu[1], uu[2], uu[3]);

  float vals[7] = {cpos, cneg, s1, m1, s0, m0, wcl};
#pragma unroll
  for (int qq = 0; qq < 7; qq++) {
    float x = vals[qq];
    for (int o = 32; o; o >>= 1) x += __shfl_down(x, o, 64);
    if (lane == 0) red[qq][wave] = x;
  }
  __syncthreads();
  if (threadIdx.x < 7)
    part[(size_t)threadIdx.x * NBLK + blk] =
        red[threadIdx.x][0] + red[threadIdx.x][1] + red[threadIdx.x][2] + red[threadIdx.x][3];

  // ---- arrival: last block of this image computes the threshold
  __threadfence();                   // release: uarr/clsl/part visible device-wide
  __syncthreads();
  if (threadIdx.x == 0) sh_t = atomicAdd(&ctr[1 + (blk >> 6)], 1u);
  __syncthreads();
  if (sh_t != BPI - 1) return;
  __threadfence();                   // acquire: see the other 63 blocks' writes
  const int img = blk >> 6;

  if (threadIdx.x < 64) {
    float cp = part[0 * NBLK + img * BPI + threadIdx.x];
    float cn = part[1 * NBLK + img * BPI + threadIdx.x];
    for (int o = 32; o; o >>= 1) { cp += __shfl_down(cp, o, 64); cn += __shfl_down(cn, o, 64); }
    if (threadIdx.x == 0) { sh_np = (unsigned)(cp + 0.5f); sh_nn = (unsigned)(cn + 0.5f); }
  }
  __syncthreads();
  unsigned npos = sh_np, nneg = sh_nn;
  unsigned k = min(3u * npos, nneg);
  if (npos == 0u || k == 0u || k >= nneg) {
    // use_all OR k==n_neg: select all negatives (pos pixels carry 0xFFFFFFFF)
    if (threadIdx.x == 0) stats[img] = 0xFFFFFFFEu;
    return;
  }

  // ---- exact k-th smallest of the image's 65536 u values (sentinels are
  // 0xFFFFFFFF = +max; k <= nneg guarantees crossing stays below them).
  // 3-level LDS histogram refinement: 12 + 12 + 8 bits. No CAP, exact.
  const uint4* u4 = (const uint4*)(uarr + (size_t)img * HW);
  // level 1: hi-12
  for (int j = threadIdx.x; j < 4096; j += NT) lhist[j] = 0;
  __syncthreads();
  for (int j = threadIdx.x; j < HW / 4; j += NT) {
    uint4 v = u4[j];
    atomicAdd(&lhist[v.x >> 20], 1u);
    atomicAdd(&lhist[v.y >> 20], 1u);
    atomicAdd(&lhist[v.z >> 20], 1u);
    atomicAdd(&lhist[v.w >> 20], 1u);
  }
  __syncthreads();
  histSelect(lhist, 4096, k, wt, &shb, &shr);
  unsigned B1 = shb, r1 = shr;
  // level 2: mid-12 within B1
  for (int j = threadIdx.x; j < 4096; j += NT) lhist[j] = 0;
  __syncthreads();
  for (int j = threadIdx.x; j < HW / 4; j += NT) {
    uint4 v = u4[j];
    if ((v.x >> 20) == B1) atomicAdd(&lhist[(v.x >> 8) & 0xFFFu], 1u);
    if ((v.y >> 20) == B1) atomicAdd(&lhist[(v.y >> 8) & 0xFFFu], 1u);
    if ((v.z >> 20) == B1) atomicAdd(&lhist[(v.z >> 8) & 0xFFFu], 1u);
    if ((v.w >> 20) == B1) atomicAdd(&lhist[(v.w >> 8) & 0xFFFu], 1u);
  }
  __syncthreads();
  histSelect(lhist, 4096, r1, wt, &shb, &shr);
  unsigned B2 = shb, r2 = shr;
  unsigned hi24 = (B1 << 12) | B2;
  // level 3: low-8 within hi24
  for (int j = threadIdx.x; j < 256; j += NT) lhist[j] = 0;
  __syncthreads();
  for (int j = threadIdx.x; j < HW / 4; j += NT) {
    uint4 v = u4[j];
    if ((v.x >> 8) == hi24) atomicAdd(&lhist[v.x & 0xFFu], 1u);
    if ((v.y >> 8) == hi24) atomicAdd(&lhist[v.y & 0xFFu], 1u);
    if ((v.z >> 8) == hi24) atomicAdd(&lhist[v.z & 0xFFu], 1u);
    if ((v.w >> 8) == hi24) atomicAdd(&lhist[v.w & 0xFFu], 1u);
  }
  __syncthreads();
  histSelect(lhist, 256, r2, wt, &shb, &shr);
  if (threadIdx.x == 0) stats[img] = (hi24 << 8) | shb;
}

// kTail: selection sums; GLOBAL last block reduces all partials + outputs.
__global__ void kTail(const unsigned* __restrict__ uarr, const float* __restrict__ clsl,
                      const unsigned* __restrict__ stats, float* __restrict__ part,
                      unsigned* __restrict__ ctr, float* __restrict__ out) {
  __shared__ float red[8][4];
  __shared__ unsigned sh_t;
  const int blk = blockIdx.x;
  const int tid = blk * NT + threadIdx.x;
  const int p0 = tid * PPT;
  const int img = p0 >> 16;
  const int lane = threadIdx.x & 63, wave = threadIdx.x >> 6;

  unsigned thr = stats[img];
  uint4 u = *(const uint4*)(uarr + p0);
  float4 c = *(const float4*)(clsl + p0);
  float cnt = 0.f, sum = 0.f;
  if (u.x <= thr) { cnt += 1.f; sum += c.x; }
  if (u.y <= thr) { cnt += 1.f; sum += c.y; }
  if (u.z <= thr) { cnt += 1.f; sum += c.z; }
  if (u.w <= thr) { cnt += 1.f; sum += c.w; }
  for (int o = 32; o; o >>= 1) { cnt += __shfl_down(cnt, o, 64); sum += __shfl_down(sum, o, 64); }
  if (lane == 0) { red[0][wave] = cnt; red[1][wave] = sum; }
  __syncthreads();
  if (threadIdx.x == 0) {
    part[7 * NBLK + blk] = red[0][0] + red[0][1] + red[0][2] + red[0][3];
    part[8 * NBLK + blk] = red[1][0] + red[1][1] + red[1][2] + red[1][3];
  }
  __threadfence();
  __syncthreads();
  if (threadIdx.x == 0) sh_t = atomicAdd(&ctr[0], 1u);
  __syncthreads();
  if (sh_t != NBLK - 1) return;
  __threadfence();
  // reduce slots {0, 2,3,4,5,6, 7, 8} over NBLK blocks
  const int slot[8] = {0, 2, 3, 4, 5, 6, 7, 8};
#pragma unroll
  for (int s = 0; s < 8; s++) {
    const float* p = part + (size_t)slot[s] * NBLK;
    float x = 0.f;
    for (int t = threadIdx.x; t < NBLK; t += NT) x += p[t];
    for (int o = 32; o; o >>= 1) x += __shfl_down(x, o, 64);
    if (lane == 0) red[s][wave] = x;
  }
  __syncthreads();
  if (threadIdx.x == 0) {
    float r[8];
#pragma unroll
    for (int s = 0; s < 8; s++) r[s] = red[s][0] + red[s][1] + red[s][2] + red[s][3];
    float npos = r[0], s1 = r[1], m1 = r[2], s0 = r[3], m0 = r[4], wcl = r[5];
    float nsel = r[6], selsum = r[7];
    out[0] = 2.f * (wcl + selsum) / (npos + nsel);
    out[1] = (npos > 0.5f) ? (s1 / m1 + s0 / m0) : 0.f;
  }
}

extern "C" void kernel_launch(void* const* d_in, const int* in_sizes, int n_in,
                              void* d_out, int out_size, void* d_ws, size_t ws_size,
                              hipStream_t stream) {
  const float* target = (const float*)d_in[0];   // (16,256,256,10)
  const float* logits = (const float*)d_in[1];   // (16,10,256,256)
  float* out = (float*)d_out;                    // [cls_loss*2, link_loss]
  char* ws = (char*)d_ws;

  unsigned* uarr  = (unsigned*)(ws + UARR_OFF);
  float*    clsl  = (float*)(ws + CLSL_OFF);
  float*    part  = (float*)(ws + PART_OFF);
  unsigned* stats = (unsigned*)(ws + STATS_OFF);
  unsigned* ctr   = (unsigned*)(ws + CTR_OFF);

  hipMemsetAsync(ctr, 0, 128, stream);           // 17 arrival counters
  kMain<<<NBLK, NT, 0, stream>>>(target, logits, uarr, clsl, part, stats, ctr);
  kTail<<<NBLK, NT, 0, stream>>>(uarr, clsl, stats, part, ctr, out);
}

// Round 7
// 113.025 us; speedup vs baseline: 2.8224x; 2.8224x over previous
//
#include <hip/hip_runtime.h>
#include <math.h>

// Problem constants (fixed by setup_inputs)
#define BB   16
#define HW   65536          // 256*256
#define NPIX (BB * HW)      // 1,048,576
#define NT   256
#define PPT  4
#define NBLK (NPIX / (NT * PPT))   // 1024 blocks
#define BPI  (NBLK / BB)           // 64 blocks per image

// ws layout (bytes)
#define UARR_OFF  0ull                              // 4 MB
#define CLSL_OFF  (4ull << 20)                      // 4 MB
// 8 partial arrays of NBLK floats (plain stores, no atomics):
//  0 pos  1 neg  2 s1  3 m1  4 s0  5 m0  6 wcl  7 negsum(=sum clsl over neg)
#define PART_OFF  (8ull << 20)
#define STATS_OFF ((8ull << 20) + (64ull << 10))
#define CTR_OFF   ((8ull << 20) + (128ull << 10))   // 1 u32 arrival counter

// stats layout (index into float/u32 view)
#define S_NPOS    0    // [16] u32 per-image pos count
#define F_SELCNT  16   // [16] float per-image selected-neg count
#define F_SELSUM  32   // [16] float per-image sum(clsl over selected)
#define F_GLB     48   // [5] float: s1,m1,s0,m0,wcl

// monotone unsigned mapping of float bits (ascending float -> ascending uint)
__device__ __forceinline__ unsigned fmap(float x) {
  unsigned b = __float_as_uint(x);
  return (b & 0x80000000u) ? ~b : (b | 0x80000000u);
}

// log(1 + e^{-|d|}) with native exp/log: arg of log is in (1,2] -> accurate
__device__ __forceinline__ float softplus_neg_abs(float d) {
  return __logf(1.f + __expf(-fabsf(d)));
}

// Crossing search for rank k in an LDS histogram (nbins multiple of 256).
__device__ __forceinline__ void histSelect(unsigned* lhist, int nbins, unsigned k,
                                           unsigned* wt, unsigned* sh_bin,
                                           unsigned* sh_rank) {
  int lane = threadIdx.x & 63, wave = threadIdx.x >> 6;
  int per = nbins >> 8;
  unsigned s = 0;
  for (int j = 0; j < per; j++) s += lhist[threadIdx.x * per + j];
  unsigned x = s;
  for (int o = 1; o < 64; o <<= 1) { unsigned v = __shfl_up(x, o, 64); if (lane >= o) x += v; }
  if (lane == 63) wt[wave] = x;
  __syncthreads();
  unsigned woff = 0;
  for (int w = 0; w < wave; w++) woff += wt[w];
  unsigned incl = x + woff, excl = incl - s;
  if (excl < k && k <= incl) {
    unsigned cum = excl;
    for (int j = 0; j < per; j++) {
      unsigned c = lhist[threadIdx.x * per + j];
      if (k <= cum + c) { *sh_bin = (unsigned)(threadIdx.x * per + j); *sh_rank = k - cum; break; }
      cum += c;
    }
  }
  __syncthreads();
}

// kA: one fat per-pixel pass. sched_barrier(0) pins all 20 float4 loads
// ABOVE the compute so they issue back-to-back (MLP=20/thread); at the
// compiler's default 48-VGPR schedule only ~4 were in flight (1.25 TB/s).
__global__ __launch_bounds__(NT, 4) void kA(
    const float* __restrict__ target, const float* __restrict__ logits,
    unsigned* __restrict__ uarr, float* __restrict__ clsl,
    float* __restrict__ part, unsigned* __restrict__ ctr) {
  if (blockIdx.x == 0 && threadIdx.x == 0) ctr[0] = 0u;   // arrival ctr for kThresh

  const int tid = blockIdx.x * NT + threadIdx.x;
  const int p0 = tid * PPT;          // 4 consecutive pixels, same image
  const int b = p0 >> 16;
  const int hw = p0 & 65535;
  const int lane = threadIdx.x & 63, wave = threadIdx.x >> 6;

  const float4* t4 = (const float4*)(target + (size_t)p0 * 10);
  const float* lg = logits + (size_t)b * 10 * HW + hw;
  float4 T[10], L[10];
#pragma unroll
  for (int j = 0; j < 10; j++) T[j] = t4[j];
#pragma unroll
  for (int c = 0; c < 10; c++) L[c] = *(const float4*)(lg + (size_t)c * HW);
  __builtin_amdgcn_sched_barrier(0);   // keep all loads above the compute

  float tf[40], lf[40];
#pragma unroll
  for (int j = 0; j < 10; j++) {
    tf[4 * j] = T[j].x; tf[4 * j + 1] = T[j].y; tf[4 * j + 2] = T[j].z; tf[4 * j + 3] = T[j].w;
    lf[4 * j] = L[j].x; lf[4 * j + 1] = L[j].y; lf[4 * j + 2] = L[j].z; lf[4 * j + 3] = L[j].w;
  }

  float cpos = 0.f, cneg = 0.f, s1 = 0.f, m1 = 0.f, s0 = 0.f, m0 = 0.f, wcl = 0.f;
  float negsum = 0.f;
  float cl4[4];
  unsigned uu[4];
#pragma unroll
  for (int q = 0; q < 4; q++) {
    float label = tf[10 * q];
    float wgt   = tf[10 * q + 1];
    bool pos = label > 0.f;
    bool neg = label == 0.f;
    float l0 = lf[0 * 4 + q], l1 = lf[1 * 4 + q];
    float d = l0 - l1;
    float cl = fmaxf(l0, l1) + softplus_neg_abs(d) - (pos ? l1 : l0);
    cl4[q] = cl;
    wcl += cl * wgt;
    cpos += pos ? 1.f : 0.f;
    cneg += neg ? 1.f : 0.f;
    if (neg) negsum += cl;
    unsigned u = fmap(d);            // score = sigmoid(d) monotone in d
    uu[q] = neg ? u : 0xFFFFFFFFu;   // finite d never maps to 0xFFFFFFFF
#pragma unroll
    for (int n = 0; n < 4; n++) {
      float a = lf[(2 + n) * 4 + q]; // class-0 logit
      float c = lf[(6 + n) * 4 + q]; // class-1 logit
      float ce0 = fmaxf(a, c) + softplus_neg_abs(a - c);
      int lab = (int)tf[10 * q + 2 + n];
      float ce = ce0 - (lab ? c : a);
      float w = tf[10 * q + 6 + n];
      if (lab) { m1 += w; s1 += w * ce; }
      else     { m0 += w; s0 += w * ce; }
    }
  }
  *(float4*)(clsl + p0) = make_float4(cl4[0], cl4[1], cl4[2], cl4[3]);
  *(uint4*)(uarr + p0)  = make_uint4(uu[0], uu[1], uu[2], uu[3]);

  float vals[8] = {cpos, cneg, s1, m1, s0, m0, wcl, negsum};
  __shared__ float red[8][4];
#pragma unroll
  for (int qq = 0; qq < 8; qq++) {
    float x = vals[qq];
    for (int o = 32; o; o >>= 1) x += __shfl_down(x, o, 64);
    if (lane == 0) red[qq][wave] = x;
  }
  __syncthreads();
  if (threadIdx.x < 8)
    part[(size_t)threadIdx.x * NBLK + blockIdx.x] =
        red[threadIdx.x][0] + red[threadIdx.x][1] + red[threadIdx.x][2] + red[threadIdx.x][3];
}

// kThresh: 16 blocks, one per image. Reduce per-image partials; OHEM shortcut
// or exact in-LDS 3-level radix select + image scan. Block 0 also reduces the
// 5 global float slots. 16-block arrival; last block assembles both outputs.
__global__ void kThresh(const unsigned* __restrict__ uarr, const float* __restrict__ clsl,
                        const float* __restrict__ part, unsigned* __restrict__ stats,
                        unsigned* __restrict__ ctr, float* __restrict__ out) {
  __shared__ unsigned lhist[4096];
  __shared__ unsigned wt[4];
  __shared__ unsigned shb, shr;
  __shared__ float shv[3];
  __shared__ float red2[5][4];
  __shared__ unsigned sh_t;
  const int img = blockIdx.x;
  const int lane = threadIdx.x & 63, wave = threadIdx.x >> 6;
  float* fstats = (float*)stats;

  // per-image reductions of slots 0 (pos), 1 (neg), 7 (negsum): 64 values each
  if (threadIdx.x < 64) {
    float cp = part[0 * NBLK + img * BPI + threadIdx.x];
    float cn = part[1 * NBLK + img * BPI + threadIdx.x];
    float ns = part[7 * NBLK + img * BPI + threadIdx.x];
    for (int o = 32; o; o >>= 1) {
      cp += __shfl_down(cp, o, 64);
      cn += __shfl_down(cn, o, 64);
      ns += __shfl_down(ns, o, 64);
    }
    if (threadIdx.x == 0) { shv[0] = cp; shv[1] = cn; shv[2] = ns; }
  }
  // block 0: reduce global slots 2..6 (s1,m1,s0,m0,wcl) over NBLK
  if (img == 0) {
#pragma unroll
    for (int s = 0; s < 5; s++) {
      const float* p = part + (size_t)(2 + s) * NBLK;
      float x = 0.f;
      for (int t = threadIdx.x; t < NBLK; t += NT) x += p[t];
      for (int o = 32; o; o >>= 1) x += __shfl_down(x, o, 64);
      if (lane == 0) red2[s][wave] = x;
    }
  }
  __syncthreads();
  if (img == 0 && threadIdx.x < 5)
    fstats[F_GLB + threadIdx.x] = red2[threadIdx.x][0] + red2[threadIdx.x][1] +
                                  red2[threadIdx.x][2] + red2[threadIdx.x][3];

  unsigned npos = (unsigned)(shv[0] + 0.5f);
  unsigned nneg = (unsigned)(shv[1] + 0.5f);
  float negsum = shv[2];
  if (threadIdx.x == 0) stats[S_NPOS + img] = npos;

  unsigned k = min(3u * npos, nneg);
  if (npos == 0u || k == 0u || k >= nneg) {
    // use_all OR k==n_neg (thr = max neg score): select ALL negatives.
    if (threadIdx.x == 0) { fstats[F_SELCNT + img] = (float)nneg; fstats[F_SELSUM + img] = negsum; }
  } else {
    // exact k-th smallest of this image's 64K u values (sentinels = +max).
    const uint4* u4 = (const uint4*)(uarr + (size_t)img * HW);
    // level 1: hi-12
    for (int j = threadIdx.x; j < 4096; j += NT) lhist[j] = 0;
    __syncthreads();
    for (int j = threadIdx.x; j < HW / 4; j += NT) {
      uint4 v = u4[j];
      atomicAdd(&lhist[v.x >> 20], 1u);
      atomicAdd(&lhist[v.y >> 20], 1u);
      atomicAdd(&lhist[v.z >> 20], 1u);
      atomicAdd(&lhist[v.w >> 20], 1u);
    }
    __syncthreads();
    histSelect(lhist, 4096, k, wt, &shb, &shr);
    unsigned B1 = shb, r1 = shr;
    // level 2: mid-12 within B1
    for (int j = threadIdx.x; j < 4096; j += NT) lhist[j] = 0;
    __syncthreads();
    for (int j = threadIdx.x; j < HW / 4; j += NT) {
      uint4 v = u4[j];
      if ((v.x >> 20) == B1) atomicAdd(&lhist[(v.x >> 8) & 0xFFFu], 1u);
      if ((v.y >> 20) == B1) atomicAdd(&lhist[(v.y >> 8) & 0xFFFu], 1u);
      if ((v.z >> 20) == B1) atomicAdd(&lhist[(v.z >> 8) & 0xFFFu], 1u);
      if ((v.w >> 20) == B1) atomicAdd(&lhist[(v.w >> 8) & 0xFFFu], 1u);
    }
    __syncthreads();
    histSelect(lhist, 4096, r1, wt, &shb, &shr);
    unsigned hi24 = (B1 << 12) | shb;
    unsigned r2 = shr;
    // level 3: low-8 within hi24
    for (int j = threadIdx.x; j < 256; j += NT) lhist[j] = 0;
    __syncthreads();
    for (int j = threadIdx.x; j < HW / 4; j += NT) {
      uint4 v = u4[j];
      if ((v.x >> 8) == hi24) atomicAdd(&lhist[v.x & 0xFFu], 1u);
      if ((v.y >> 8) == hi24) atomicAdd(&lhist[v.y & 0xFFu], 1u);
      if ((v.z >> 8) == hi24) atomicAdd(&lhist[v.z & 0xFFu], 1u);
      if ((v.w >> 8) == hi24) atomicAdd(&lhist[v.w & 0xFFu], 1u);
    }
    __syncthreads();
    histSelect(lhist, 256, r2, wt, &shb, &shr);
    unsigned thr = (hi24 << 8) | shb;
    // scan the image: selcnt = #{u <= thr}, selsum = sum clsl over selected
    const float4* c4 = (const float4*)(clsl + (size_t)img * HW);
    float cnt = 0.f, sum = 0.f;
    for (int j = threadIdx.x; j < HW / 4; j += NT) {
      uint4 v = u4[j];
      float4 c = c4[j];
      if (v.x <= thr) { cnt += 1.f; sum += c.x; }
      if (v.y <= thr) { cnt += 1.f; sum += c.y; }
      if (v.z <= thr) { cnt += 1.f; sum += c.z; }
      if (v.w <= thr) { cnt += 1.f; sum += c.w; }
    }
    for (int o = 32; o; o >>= 1) { cnt += __shfl_down(cnt, o, 64); sum += __shfl_down(sum, o, 64); }
    if (lane == 0) { red2[0][wave] = cnt; red2[1][wave] = sum; }
    __syncthreads();
    if (threadIdx.x == 0) {
      fstats[F_SELCNT + img] = red2[0][0] + red2[0][1] + red2[0][2] + red2[0][3];
      fstats[F_SELSUM + img] = red2[1][0] + red2[1][1] + red2[1][2] + red2[1][3];
    }
  }

  // 16-block arrival (cheap at this scale); last block assembles outputs.
  __threadfence();
  __syncthreads();
  if (threadIdx.x == 0) sh_t = atomicAdd(&ctr[0], 1u);
  __syncthreads();
  if (sh_t != BB - 1) return;
  __threadfence();
  if (threadIdx.x == 0) {
    unsigned npos_t = 0;
    float nsel = 0.f, selsum = 0.f;
    for (int b = 0; b < BB; b++) {
      npos_t += stats[S_NPOS + b];
      nsel   += fstats[F_SELCNT + b];
      selsum += fstats[F_SELSUM + b];
    }
    float s1 = fstats[F_GLB + 0], m1 = fstats[F_GLB + 1];
    float s0 = fstats[F_GLB + 2], m0 = fstats[F_GLB + 3];
    float wcl = fstats[F_GLB + 4];
    out[0] = 2.f * (wcl + selsum) / ((float)npos_t + nsel);
    out[1] = (npos_t != 0u) ? (s1 / m1 + s0 / m0) : 0.f;
  }
}

extern "C" void kernel_launch(void* const* d_in, const int* in_sizes, int n_in,
                              void* d_out, int out_size, void* d_ws, size_t ws_size,
                              hipStream_t stream) {
  const float* target = (const float*)d_in[0];   // (16,256,256,10)
  const float* logits = (const float*)d_in[1];   // (16,10,256,256)
  float* out = (float*)d_out;                    // [cls_loss*2, link_loss]
  char* ws = (char*)d_ws;

  unsigned* uarr  = (unsigned*)(ws + UARR_OFF);
  float*    clsl  = (float*)(ws + CLSL_OFF);
  float*    part  = (float*)(ws + PART_OFF);
  unsigned* stats = (unsigned*)(ws + STATS_OFF);
  unsigned* ctr   = (unsigned*)(ws + CTR_OFF);

  kA<<<NBLK, NT, 0, stream>>>(target, logits, uarr, clsl, part, ctr);
  kThresh<<<BB, NT, 0, stream>>>(uarr, clsl, part, stats, ctr, out);
}

// Round 8
// 111.330 us; speedup vs baseline: 2.8653x; 1.0152x over previous
//
#include <hip/hip_runtime.h>
#include <math.h>

// Problem constants (fixed by setup_inputs)
#define BB   16
#define HW   65536          // 256*256
#define NPIX (BB * HW)      // 1,048,576
#define NT   256
#define PPT  4
#define NBLK (NPIX / (NT * PPT))   // 1024 blocks
#define BPI  (NBLK / BB)           // 64 blocks per image
#define S44  11             // LDS group stride in float4 units (10 + 1 pad)

// ws layout (bytes)
#define UARR_OFF  0ull                              // 4 MB
#define CLSL_OFF  (4ull << 20)                      // 4 MB
// 8 partial arrays of NBLK floats (plain stores, no atomics):
//  0 pos  1 neg  2 s1  3 m1  4 s0  5 m0  6 wcl  7 negsum(=sum clsl over neg)
#define PART_OFF  (8ull << 20)
#define STATS_OFF ((8ull << 20) + (64ull << 10))
#define CTR_OFF   ((8ull << 20) + (128ull << 10))   // 1 u32 arrival counter

// stats layout (index into float/u32 view)
#define S_NPOS    0    // [16] u32 per-image pos count
#define F_SELCNT  16   // [16] float per-image selected-neg count
#define F_SELSUM  32   // [16] float per-image sum(clsl over selected)
#define F_GLB     48   // [5] float: s1,m1,s0,m0,wcl

// monotone unsigned mapping of float bits (ascending float -> ascending uint)
__device__ __forceinline__ unsigned fmap(float x) {
  unsigned b = __float_as_uint(x);
  return (b & 0x80000000u) ? ~b : (b | 0x80000000u);
}

// log(1 + e^{-|d|}) with native exp/log: arg of log is in (1,2] -> accurate
__device__ __forceinline__ float softplus_neg_abs(float d) {
  return __logf(1.f + __expf(-fabsf(d)));
}

// Crossing search for rank k in an LDS histogram (nbins multiple of 256).
__device__ __forceinline__ void histSelect(unsigned* lhist, int nbins, unsigned k,
                                           unsigned* wt, unsigned* sh_bin,
                                           unsigned* sh_rank) {
  int lane = threadIdx.x & 63, wave = threadIdx.x >> 6;
  int per = nbins >> 8;
  unsigned s = 0;
  for (int j = 0; j < per; j++) s += lhist[threadIdx.x * per + j];
  unsigned x = s;
  for (int o = 1; o < 64; o <<= 1) { unsigned v = __shfl_up(x, o, 64); if (lane >= o) x += v; }
  if (lane == 63) wt[wave] = x;
  __syncthreads();
  unsigned woff = 0;
  for (int w = 0; w < wave; w++) woff += wt[w];
  unsigned incl = x + woff, excl = incl - s;
  if (excl < k && k <= incl) {
    unsigned cum = excl;
    for (int j = 0; j < per; j++) {
      unsigned c = lhist[threadIdx.x * per + j];
      if (k <= cum + c) { *sh_bin = (unsigned)(threadIdx.x * per + j); *sh_rank = k - cum; break; }
      cum += c;
    }
  }
  __syncthreads();
}

// kA: one fat per-pixel pass. Target (64-way-scattered layout) is staged
// through LDS so its 10 global loads are fully coalesced; logits loads were
// already coalesced. sched_barrier(0) pins all 20 loads above the compute.
__global__ __launch_bounds__(NT, 3) void kA(
    const float* __restrict__ target, const float* __restrict__ logits,
    unsigned* __restrict__ uarr, float* __restrict__ clsl,
    float* __restrict__ part, unsigned* __restrict__ ctr) {
  __shared__ float4 sT[NT * S44];      // 45056 B; stride-44-word groups: same
  __shared__ float red[8][4];          // bank pattern as plain float4 array
  if (blockIdx.x == 0 && threadIdx.x == 0) ctr[0] = 0u;   // arrival ctr for kThresh

  const int tid = blockIdx.x * NT + threadIdx.x;
  const int p0 = tid * PPT;            // 4 consecutive pixels, same image
  const int b = p0 >> 16;
  const int hw = p0 & 65535;
  const int lane = threadIdx.x & 63, wave = threadIdx.x >> 6;

  // coalesced target stage: the block's 1024 pixels = 2560 contiguous float4
  const float4* tBase = (const float4*)(target + (size_t)blockIdx.x * (NT * PPT) * 10);
  float4 T[10];
#pragma unroll
  for (int j = 0; j < 10; j++) T[j] = tBase[threadIdx.x + NT * j];
  const float* lg = logits + (size_t)b * 10 * HW + hw;
  float4 L[10];
#pragma unroll
  for (int c = 0; c < 10; c++) L[c] = *(const float4*)(lg + (size_t)c * HW);
  __builtin_amdgcn_sched_barrier(0);   // keep all 20 loads above everything

  // scatter target chunks into padded LDS groups (chunk c -> group c/10)
#pragma unroll
  for (int j = 0; j < 10; j++) {
    int c = threadIdx.x + NT * j;
    sT[S44 * (c / 10) + (c % 10)] = T[j];
  }
  __syncthreads();

  float tf[40], lf[40];
#pragma unroll
  for (int m = 0; m < 10; m++) {
    float4 v = sT[S44 * threadIdx.x + m];
    tf[4 * m] = v.x; tf[4 * m + 1] = v.y; tf[4 * m + 2] = v.z; tf[4 * m + 3] = v.w;
    lf[4 * m] = L[m].x; lf[4 * m + 1] = L[m].y; lf[4 * m + 2] = L[m].z; lf[4 * m + 3] = L[m].w;
  }

  float cpos = 0.f, cneg = 0.f, s1 = 0.f, m1 = 0.f, s0 = 0.f, m0 = 0.f, wcl = 0.f;
  float negsum = 0.f;
  float cl4[4];
  unsigned uu[4];
#pragma unroll
  for (int q = 0; q < 4; q++) {
    float label = tf[10 * q];
    float wgt   = tf[10 * q + 1];
    bool pos = label > 0.f;
    bool neg = label == 0.f;
    float l0 = lf[0 * 4 + q], l1 = lf[1 * 4 + q];
    float d = l0 - l1;
    float cl = fmaxf(l0, l1) + softplus_neg_abs(d) - (pos ? l1 : l0);
    cl4[q] = cl;
    wcl += cl * wgt;
    cpos += pos ? 1.f : 0.f;
    cneg += neg ? 1.f : 0.f;
    if (neg) negsum += cl;
    unsigned u = fmap(d);              // score = sigmoid(d) monotone in d
    uu[q] = neg ? u : 0xFFFFFFFFu;     // finite d never maps to 0xFFFFFFFF
#pragma unroll
    for (int n = 0; n < 4; n++) {
      float a = lf[(2 + n) * 4 + q];   // class-0 logit
      float c = lf[(6 + n) * 4 + q];   // class-1 logit
      float ce0 = fmaxf(a, c) + softplus_neg_abs(a - c);
      int lab = (int)tf[10 * q + 2 + n];
      float ce = ce0 - (lab ? c : a);
      float w = tf[10 * q + 6 + n];
      if (lab) { m1 += w; s1 += w * ce; }
      else     { m0 += w; s0 += w * ce; }
    }
  }
  *(float4*)(clsl + p0) = make_float4(cl4[0], cl4[1], cl4[2], cl4[3]);
  *(uint4*)(uarr + p0)  = make_uint4(uu[0], uu[1], uu[2], uu[3]);

  float vals[8] = {cpos, cneg, s1, m1, s0, m0, wcl, negsum};
#pragma unroll
  for (int qq = 0; qq < 8; qq++) {
    float x = vals[qq];
    for (int o = 32; o; o >>= 1) x += __shfl_down(x, o, 64);
    if (lane == 0) red[qq][wave] = x;
  }
  __syncthreads();
  if (threadIdx.x < 8)
    part[(size_t)threadIdx.x * NBLK + blockIdx.x] =
        red[threadIdx.x][0] + red[threadIdx.x][1] + red[threadIdx.x][2] + red[threadIdx.x][3];
}

// kThresh: 16 blocks, one per image. Reduce per-image partials; OHEM shortcut
// or exact in-LDS 3-level radix select + image scan. Block 0 also reduces the
// 5 global float slots. 16-block arrival; last block assembles both outputs.
__global__ void kThresh(const unsigned* __restrict__ uarr, const float* __restrict__ clsl,
                        const float* __restrict__ part, unsigned* __restrict__ stats,
                        unsigned* __restrict__ ctr, float* __restrict__ out) {
  __shared__ unsigned lhist[4096];
  __shared__ unsigned wt[4];
  __shared__ unsigned shb, shr;
  __shared__ float shv[3];
  __shared__ float red2[5][4];
  __shared__ unsigned sh_t;
  const int img = blockIdx.x;
  const int lane = threadIdx.x & 63, wave = threadIdx.x >> 6;
  float* fstats = (float*)stats;

  // per-image reductions of slots 0 (pos), 1 (neg), 7 (negsum): 64 values each
  if (threadIdx.x < 64) {
    float cp = part[0 * NBLK + img * BPI + threadIdx.x];
    float cn = part[1 * NBLK + img * BPI + threadIdx.x];
    float ns = part[7 * NBLK + img * BPI + threadIdx.x];
    for (int o = 32; o; o >>= 1) {
      cp += __shfl_down(cp, o, 64);
      cn += __shfl_down(cn, o, 64);
      ns += __shfl_down(ns, o, 64);
    }
    if (threadIdx.x == 0) { shv[0] = cp; shv[1] = cn; shv[2] = ns; }
  }
  // block 0: reduce global slots 2..6 (s1,m1,s0,m0,wcl) over NBLK
  if (img == 0) {
#pragma unroll
    for (int s = 0; s < 5; s++) {
      const float* p = part + (size_t)(2 + s) * NBLK;
      float x = 0.f;
      for (int t = threadIdx.x; t < NBLK; t += NT) x += p[t];
      for (int o = 32; o; o >>= 1) x += __shfl_down(x, o, 64);
      if (lane == 0) red2[s][wave] = x;
    }
  }
  __syncthreads();
  if (img == 0 && threadIdx.x < 5)
    fstats[F_GLB + threadIdx.x] = red2[threadIdx.x][0] + red2[threadIdx.x][1] +
                                  red2[threadIdx.x][2] + red2[threadIdx.x][3];

  unsigned npos = (unsigned)(shv[0] + 0.5f);
  unsigned nneg = (unsigned)(shv[1] + 0.5f);
  float negsum = shv[2];
  if (threadIdx.x == 0) stats[S_NPOS + img] = npos;

  unsigned k = min(3u * npos, nneg);
  if (npos == 0u || k == 0u || k >= nneg) {
    // use_all OR k==n_neg (thr = max neg score): select ALL negatives.
    if (threadIdx.x == 0) { fstats[F_SELCNT + img] = (float)nneg; fstats[F_SELSUM + img] = negsum; }
  } else {
    // exact k-th smallest of this image's 64K u values (sentinels = +max).
    const uint4* u4 = (const uint4*)(uarr + (size_t)img * HW);
    // level 1: hi-12
    for (int j = threadIdx.x; j < 4096; j += NT) lhist[j] = 0;
    __syncthreads();
    for (int j = threadIdx.x; j < HW / 4; j += NT) {
      uint4 v = u4[j];
      atomicAdd(&lhist[v.x >> 20], 1u);
      atomicAdd(&lhist[v.y >> 20], 1u);
      atomicAdd(&lhist[v.z >> 20], 1u);
      atomicAdd(&lhist[v.w >> 20], 1u);
    }
    __syncthreads();
    histSelect(lhist, 4096, k, wt, &shb, &shr);
    unsigned B1 = shb, r1 = shr;
    // level 2: mid-12 within B1
    for (int j = threadIdx.x; j < 4096; j += NT) lhist[j] = 0;
    __syncthreads();
    for (int j = threadIdx.x; j < HW / 4; j += NT) {
      uint4 v = u4[j];
      if ((v.x >> 20) == B1) atomicAdd(&lhist[(v.x >> 8) & 0xFFFu], 1u);
      if ((v.y >> 20) == B1) atomicAdd(&lhist[(v.y >> 8) & 0xFFFu], 1u);
      if ((v.z >> 20) == B1) atomicAdd(&lhist[(v.z >> 8) & 0xFFFu], 1u);
      if ((v.w >> 20) == B1) atomicAdd(&lhist[(v.w >> 8) & 0xFFFu], 1u);
    }
    __syncthreads();
    histSelect(lhist, 4096, r1, wt, &shb, &shr);
    unsigned hi24 = (B1 << 12) | shb;
    unsigned r2 = shr;
    // level 3: low-8 within hi24
    for (int j = threadIdx.x; j < 256; j += NT) lhist[j] = 0;
    __syncthreads();
    for (int j = threadIdx.x; j < HW / 4; j += NT) {
      uint4 v = u4[j];
      if ((v.x >> 8) == hi24) atomicAdd(&lhist[v.x & 0xFFu], 1u);
      if ((v.y >> 8) == hi24) atomicAdd(&lhist[v.y & 0xFFu], 1u);
      if ((v.z >> 8) == hi24) atomicAdd(&lhist[v.z & 0xFFu], 1u);
      if ((v.w >> 8) == hi24) atomicAdd(&lhist[v.w & 0xFFu], 1u);
    }
    __syncthreads();
    histSelect(lhist, 256, r2, wt, &shb, &shr);
    unsigned thr = (hi24 << 8) | shb;
    // scan the image: selcnt = #{u <= thr}, selsum = sum clsl over selected
    const float4* c4 = (const float4*)(clsl + (size_t)img * HW);
    float cnt = 0.f, sum = 0.f;
    for (int j = threadIdx.x; j < HW / 4; j += NT) {
      uint4 v = u4[j];
      float4 c = c4[j];
      if (v.x <= thr) { cnt += 1.f; sum += c.x; }
      if (v.y <= thr) { cnt += 1.f; sum += c.y; }
      if (v.z <= thr) { cnt += 1.f; sum += c.z; }
      if (v.w <= thr) { cnt += 1.f; sum += c.w; }
    }
    for (int o = 32; o; o >>= 1) { cnt += __shfl_down(cnt, o, 64); sum += __shfl_down(sum, o, 64); }
    if (lane == 0) { red2[0][wave] = cnt; red2[1][wave] = sum; }
    __syncthreads();
    if (threadIdx.x == 0) {
      fstats[F_SELCNT + img] = red2[0][0] + red2[0][1] + red2[0][2] + red2[0][3];
      fstats[F_SELSUM + img] = red2[1][0] + red2[1][1] + red2[1][2] + red2[1][3];
    }
  }

  // 16-block arrival (cheap at this scale); last block assembles outputs.
  __threadfence();
  __syncthreads();
  if (threadIdx.x == 0) sh_t = atomicAdd(&ctr[0], 1u);
  __syncthreads();
  if (sh_t != BB - 1) return;
  __threadfence();
  if (threadIdx.x == 0) {
    unsigned npos_t = 0;
    float nsel = 0.f, selsum = 0.f;
    for (int b = 0; b < BB; b++) {
      npos_t += stats[S_NPOS + b];
      nsel   += fstats[F_SELCNT + b];
      selsum += fstats[F_SELSUM + b];
    }
    float s1 = fstats[F_GLB + 0], m1 = fstats[F_GLB + 1];
    float s0 = fstats[F_GLB + 2], m0 = fstats[F_GLB + 3];
    float wcl = fstats[F_GLB + 4];
    out[0] = 2.f * (wcl + selsum) / ((float)npos_t + nsel);
    out[1] = (npos_t != 0u) ? (s1 / m1 + s0 / m0) : 0.f;
  }
}

extern "C" void kernel_launch(void* const* d_in, const int* in_sizes, int n_in,
                              void* d_out, int out_size, void* d_ws, size_t ws_size,
                              hipStream_t stream) {
  const float* target = (const float*)d_in[0];   // (16,256,256,10)
  const float* logits = (const float*)d_in[1];   // (16,10,256,256)
  float* out = (float*)d_out;                    // [cls_loss*2, link_loss]
  char* ws = (char*)d_ws;

  unsigned* uarr  = (unsigned*)(ws + UARR_OFF);
  float*    clsl  = (float*)(ws + CLSL_OFF);
  float*    part  = (float*)(ws + PART_OFF);
  unsigned* stats = (unsigned*)(ws + STATS_OFF);
  unsigned* ctr   = (unsigned*)(ws + CTR_OFF);

  kA<<<NBLK, NT, 0, stream>>>(target, logits, uarr, clsl, part, ctr);
  kThresh<<<BB, NT, 0, stream>>>(uarr, clsl, part, stats, ctr, out);
}